// Round 1
// 415.720 us; speedup vs baseline: 1.1147x; 1.1147x over previous
//
#include <hip/hip_runtime.h>

#define H    64
#define TT   512
#define NB   16
#define OUTD 3
#define BTOT 4096
#define INF  6

typedef _Float16 f16;
typedef _Float16 f16x8 __attribute__((ext_vector_type(8)));
typedef float    f32x4 __attribute__((ext_vector_type(4)));
typedef float    f32x2 __attribute__((ext_vector_type(2)));

// plane row stride (f16 elems): cols 0-63 h0 | 64-127 h1 | 128-135 x | pad
#define AS 168

#define LOG2E 1.44269504088896340736f
#define KSC   (2.0f * LOG2E)

static __device__ __forceinline__ f32x2 pk_fma(f32x2 a, f32x2 b, f32x2 c) {
#if __has_builtin(__builtin_elementwise_fma)
    return __builtin_elementwise_fma(a, b, c);
#else
    f32x2 r; r.x = __builtin_fmaf(a.x, b.x, c.x); r.y = __builtin_fmaf(a.y, b.y, c.y);
    return r;
#endif
}

// Fused LSTM cell update for a ROW PAIR, written on float2 ext-vectors so the
// backend emits v_pk_{add,mul,fma}_f32 (full-rate packed fp32, gfx90a+).
// Pre-activations arrive pre-scaled: ai,af,ao by log2e; ag by 2*log2e. C is the
// cell state pre-scaled by 2*log2e, updated in place. Returns h pair.
// Transcendentals (exp2/rcp) have no packed form and stay scalar: 12 per pair.
__device__ __forceinline__ f32x2 lstm_cell2(f32x2 ai, f32x2 af, f32x2 ag, f32x2 ao,
                                            f32x2& C) {
    f32x2 ei, ef, eg, eo;
    ei.x = __builtin_amdgcn_exp2f(ai.x); ei.y = __builtin_amdgcn_exp2f(ai.y);
    ef.x = __builtin_amdgcn_exp2f(af.x); ef.y = __builtin_amdgcn_exp2f(af.y);
    eg.x = __builtin_amdgcn_exp2f(ag.x); eg.y = __builtin_amdgcn_exp2f(ag.y);
    eo.x = __builtin_amdgcn_exp2f(ao.x); eo.y = __builtin_amdgcn_exp2f(ao.y);
    f32x2 A  = ei + 1.0f;          // sigmoid(i) = ei/A
    f32x2 F  = ef + 1.0f;          // sigmoid(f) = ef/F
    f32x2 Bp = eg + 1.0f;          // tanh(g)    = (eg-1)/Bp
    f32x2 G  = eg - 1.0f;
    f32x2 P  = A * Bp;
    f32x2 PF = P * F;
    f32x2 r1; r1.x = __builtin_amdgcn_rcpf(PF.x); r1.y = __builtin_amdgcn_rcpf(PF.y);
    f32x2 n1 = ef * C * P;         // sigmoid(f)*C  * (P*F)
    f32x2 t2 = ei * G * F;         // i*g           * (P*F) / K
    f32x2 k2 = {KSC, KSC};
    C = pk_fma(k2, t2, n1) * r1;
    // h = sigmoid(o) * tanh(c):  ec = 2^C (C already 2*log2e*c), clamped vs inf
    f32x2 Cc; Cc.x = fminf(C.x, 126.0f); Cc.y = fminf(C.y, 126.0f);
    f32x2 ec; ec.x = __builtin_amdgcn_exp2f(Cc.x); ec.y = __builtin_amdgcn_exp2f(Cc.y);
    f32x2 D2 = (eo + 1.0f) * (ec + 1.0f);
    f32x2 r2; r2.x = __builtin_amdgcn_rcpf(D2.x); r2.y = __builtin_amdgcn_rcpf(D2.y);
    return eo * (ec - 1.0f) * r2;
}

// Wave-specialized layer pipeline (single-f16 state planes):
//   waves 0-3 (role 0): layer-0, compute h0(s) at slot s          (s = 0..TT-1)
//   waves 4-7 (role 1): layer-1, compute h1(s-1) at slot s        (s = 1..TT)
// One barrier per slot. h0(s) -> plane s&1 cols 0-63; h1(s-1) -> plane (s-1)&1
// cols 64-127; x(s) -> plane s&1 cols 128+. Same-slot ranges disjoint.
__launch_bounds__(512, 2)
__global__ void lstm_ws(const float* __restrict__ x,
                        const float* __restrict__ Wih0, const float* __restrict__ Whh0,
                        const float* __restrict__ bih0, const float* __restrict__ bhh0,
                        const float* __restrict__ Wih1, const float* __restrict__ Whh1,
                        const float* __restrict__ bih1, const float* __restrict__ bhh1,
                        const float* __restrict__ Wfc,  const float* __restrict__ bfc,
                        float* __restrict__ out)
{
    __shared__ __align__(16) f16 Phi[2][NB * AS];
    __shared__ float hfin[NB][H + 1];

    const int t    = threadIdx.x;
    const int u    = t & 255;
    const int role = t >> 8;
    const int wv   = u >> 6;
    const int l15  = u & 15;
    const int q    = (u >> 4) & 3;
    const int jj   = 16 * wv + l15;   // hidden column this thread owns (all 4 gates)
    const int b0   = blockIdx.x * NB;
    const int ar   = l15 * AS;
    const int ko   = q * 8;

    // ---- zero both planes ----
    {
        f16* ph = &Phi[0][0];
        for (int idx = t; idx < 2 * NB * AS; idx += 512) ph[idx] = (f16)0.0f;
    }
    __syncthreads();   // zeroing complete before x(0) store

    const bool loader = (role == 0) && (u < NB * INF);
    const int  xb = u / INF;
    const int  xf = u - xb * INF;
    if (loader)
        Phi[0][xb * AS + 128 + xf] = (f16)x[((size_t)(b0 + xb) * TT) * INF + xf];
    __syncthreads();

    if (role == 0) {
        // ================= LAYER-0 waves =================
        f16x8 wh0[2][4];   // Whh0 fragments, pre-scaled
        f16x8 wx0[4];      // Wih0 x-tile (k<6 valid on q==0)
        f32x4 bC0[4];      // bias splat, persistent C operand for first MFMA
        #pragma unroll
        for (int g = 0; g < 4; ++g) {
            const float sc = (g == 2) ? (2.0f * LOG2E) : LOG2E;
            const int n = 64 * g + jj;
            #pragma unroll
            for (int kt = 0; kt < 2; ++kt) {
                f16x8 v;
                #pragma unroll
                for (int j = 0; j < 8; ++j)
                    v[j] = (f16)(Whh0[n * H + kt * 32 + q * 8 + j] * sc);
                wh0[kt][g] = v;
            }
            f16x8 vx;
            #pragma unroll
            for (int j = 0; j < 8; ++j)
                vx[j] = (q == 0 && j < INF) ? (f16)(Wih0[n * INF + j] * sc) : (f16)0.0f;
            wx0[g] = vx;
            const float bu = (bih0[64 * g + jj] + bhh0[64 * g + jj]) * sc;
            bC0[g] = (f32x4){bu, bu, bu, bu};
        }
        f32x2 c01 = {0.f, 0.f}, c23 = {0.f, 0.f};   // cell state, pre-scaled by 2*log2e
        float xpre = 0.0f;

        // AH = plane p^1 (h0(s-1) read, x(s+1) write); BH = plane p (x(s) read, h0(s) write)
        auto stepL0 = [&](f16* __restrict__ AH, f16* __restrict__ BH, int s) {
            if (loader) {
                const int tn = (s + 1 < TT) ? (s + 1) : (TT - 1);
                xpre = x[((size_t)(b0 + xb) * TT + tn) * INF + xf];
            }
            f16x8 a0 = *(const f16x8*)&AH[ar + 0   + ko];
            f16x8 a1 = *(const f16x8*)&AH[ar + 32  + ko];
            f16x8 ax = *(const f16x8*)&BH[ar + 128 + ko];
            f32x4 accA[4];
            #pragma unroll
            for (int g = 0; g < 4; ++g) {
                f32x4 acc;   // bias enters as the C operand: no per-step init movs
                acc = __builtin_amdgcn_mfma_f32_16x16x32_f16(a0, wh0[0][g], bC0[g], 0, 0, 0);
                acc = __builtin_amdgcn_mfma_f32_16x16x32_f16(a1, wh0[1][g], acc, 0, 0, 0);
                acc = __builtin_amdgcn_mfma_f32_16x16x32_f16(ax, wx0[g],    acc, 0, 0, 0);
                accA[g] = acc;
            }
            f32x2 h01 = lstm_cell2((f32x2){accA[0][0], accA[0][1]},
                                   (f32x2){accA[1][0], accA[1][1]},
                                   (f32x2){accA[2][0], accA[2][1]},
                                   (f32x2){accA[3][0], accA[3][1]}, c01);
            f32x2 h23 = lstm_cell2((f32x2){accA[0][2], accA[0][3]},
                                   (f32x2){accA[1][2], accA[1][3]},
                                   (f32x2){accA[2][2], accA[2][3]},
                                   (f32x2){accA[3][2], accA[3][3]}, c23);
            BH[(q * 4 + 0) * AS + jj] = (f16)h01.x;
            BH[(q * 4 + 1) * AS + jj] = (f16)h01.y;
            BH[(q * 4 + 2) * AS + jj] = (f16)h23.x;
            BH[(q * 4 + 3) * AS + jj] = (f16)h23.y;
            if (loader) AH[xb * AS + 128 + xf] = (f16)xpre;
            __syncthreads();
        };

        for (int s = 0; s < TT; s += 2) {
            stepL0(Phi[1], Phi[0], s);
            stepL0(Phi[0], Phi[1], s + 1);
        }
        __syncthreads();   // slot TT (layer-1 finishes h1(TT-1))
    } else {
        // ================= LAYER-1 waves =================
        f16x8 wi1[2][4];   // Wih1 (input = h0)
        f16x8 wh1[2][4];   // Whh1 (recurrent h1)
        f32x4 bC1[4];      // bias splat, persistent C operand for first MFMA
        #pragma unroll
        for (int g = 0; g < 4; ++g) {
            const float sc = (g == 2) ? (2.0f * LOG2E) : LOG2E;
            const int n = 64 * g + jj;
            #pragma unroll
            for (int kt = 0; kt < 2; ++kt) {
                f16x8 v1, v2;
                #pragma unroll
                for (int j = 0; j < 8; ++j) {
                    const int k = kt * 32 + q * 8 + j;
                    v1[j] = (f16)(Wih1[n * H + k] * sc);
                    v2[j] = (f16)(Whh1[n * H + k] * sc);
                }
                wi1[kt][g] = v1; wh1[kt][g] = v2;
            }
            const float bu = (bih1[64 * g + jj] + bhh1[64 * g + jj]) * sc;
            bC1[g] = (f32x4){bu, bu, bu, bu};
        }
        f32x2 c01 = {0.f, 0.f}, c23 = {0.f, 0.f};   // cell state, pre-scaled by 2*log2e

        __syncthreads();   // slot 0 (layer-0 produces h0(0))

        // AH = plane p^1 (h0(s-1) read, h1(s-1) write); BH = plane p (h1(s-2) read)
        auto stepL1 = [&](f16* __restrict__ AH, f16* __restrict__ BH, int s) {
            f16x8 n0 = *(const f16x8*)&AH[ar + 0  + ko];
            f16x8 n1 = *(const f16x8*)&AH[ar + 32 + ko];
            f16x8 r0 = *(const f16x8*)&BH[ar + 64 + ko];
            f16x8 r1 = *(const f16x8*)&BH[ar + 96 + ko];
            f32x4 accB[4];
            #pragma unroll
            for (int g = 0; g < 4; ++g) {
                f32x4 acc;   // bias enters as the C operand: no per-step init movs
                acc = __builtin_amdgcn_mfma_f32_16x16x32_f16(n0, wi1[0][g], bC1[g], 0, 0, 0);
                acc = __builtin_amdgcn_mfma_f32_16x16x32_f16(n1, wi1[1][g], acc, 0, 0, 0);
                acc = __builtin_amdgcn_mfma_f32_16x16x32_f16(r0, wh1[0][g], acc, 0, 0, 0);
                acc = __builtin_amdgcn_mfma_f32_16x16x32_f16(r1, wh1[1][g], acc, 0, 0, 0);
                accB[g] = acc;
            }
            f32x2 h01 = lstm_cell2((f32x2){accB[0][0], accB[0][1]},
                                   (f32x2){accB[1][0], accB[1][1]},
                                   (f32x2){accB[2][0], accB[2][1]},
                                   (f32x2){accB[3][0], accB[3][1]}, c01);
            f32x2 h23 = lstm_cell2((f32x2){accB[0][2], accB[0][3]},
                                   (f32x2){accB[1][2], accB[1][3]},
                                   (f32x2){accB[2][2], accB[2][3]},
                                   (f32x2){accB[3][2], accB[3][3]}, c23);
            AH[(q * 4 + 0) * AS + 64 + jj] = (f16)h01.x;
            AH[(q * 4 + 1) * AS + 64 + jj] = (f16)h01.y;
            AH[(q * 4 + 2) * AS + 64 + jj] = (f16)h23.x;
            AH[(q * 4 + 3) * AS + 64 + jj] = (f16)h23.y;
            if (s == TT) {
                hfin[q * 4 + 0][jj] = h01.x;
                hfin[q * 4 + 1][jj] = h01.y;
                hfin[q * 4 + 2][jj] = h23.x;
                hfin[q * 4 + 3][jj] = h23.y;
            }
            __syncthreads();
        };

        for (int s = 1; s <= TT; s += 2) {
            stepL1(Phi[0], Phi[1], s);
            stepL1(Phi[1], Phi[0], s + 1);
        }
    }

    // ---- FC epilogue ----
    if (t < NB * OUTD) {
        const int b = t / OUTD;
        const int o = t - b * OUTD;
        float a = bfc[o];
        #pragma unroll
        for (int j = 0; j < H; ++j)
            a += Wfc[o * H + j] * hfin[b][j];
        out[(size_t)(b0 + b) * OUTD + o] = a;
    }
}

extern "C" void kernel_launch(void* const* d_in, const int* in_sizes, int n_in,
                              void* d_out, int out_size, void* d_ws, size_t ws_size,
                              hipStream_t stream) {
    const float* x    = (const float*)d_in[0];
    const float* Wih0 = (const float*)d_in[1];
    const float* Whh0 = (const float*)d_in[2];
    const float* bih0 = (const float*)d_in[3];
    const float* bhh0 = (const float*)d_in[4];
    const float* Wih1 = (const float*)d_in[5];
    const float* Whh1 = (const float*)d_in[6];
    const float* bih1 = (const float*)d_in[7];
    const float* bhh1 = (const float*)d_in[8];
    const float* Wfc  = (const float*)d_in[9];
    const float* bfc  = (const float*)d_in[10];

    dim3 grid(BTOT / NB);   // 256 blocks, 1 per CU; 8 waves = 2 waves/SIMD
    dim3 block(512);
    lstm_ws<<<grid, block, 0, stream>>>(x, Wih0, Whh0, bih0, bhh0,
                                        Wih1, Whh1, bih1, bhh1,
                                        Wfc, bfc, (float*)d_out);
}